// Round 6
// baseline (64.959 us; speedup 1.0000x reference)
//
#include <hip/hip_runtime.h>
#include <hip/hip_bf16.h>
#include <math.h>

#define N_PTS 16384
#define KNN   16
#define NCLS  20
#define BND_W 1.0f

#define THREADS 512
#define WAVES   8
#define RPW     32                   // rows per wave (2 fragments of 16)
#define RPB     (WAVES * RPW)        // 256 rows per block
#define RBLKS   (N_PTS / RPB)        // 64
#define CSPLIT  8
#define CAND_PB (N_PTS / CSPLIT)     // 2048 candidates per block
#define CHUNK   1024                 // candidates per LDS stage (64 KB)
#define NCHUNK  (CAND_PB / CHUNK)    // 2

typedef short  short8 __attribute__((ext_vector_type(8)));
typedef float  f32x4  __attribute__((ext_vector_type(4)));

// ---- bf16 helpers (RNE) ----
__device__ __forceinline__ unsigned short f2bf(float x) {
    union { __hip_bfloat16 h; unsigned short u; } cv;
    cv.h = __float2bfloat16(x);
    return cv.u;
}
__device__ __forceinline__ float bf2f(unsigned short b) {
    union { __hip_bfloat16 h; unsigned short u; } cv;
    cv.u = b;
    return __bfloat162float(cv.h);
}

// async global->LDS, 16 B per lane: LDS dest = uniform base + lane*16,
// global src = per-lane address (guide §5; m97/m104 semantics)
__device__ __forceinline__ void gload16(const void* g, void* l) {
    __builtin_amdgcn_global_load_lds(
        (const __attribute__((address_space(1))) unsigned int*)g,
        (__attribute__((address_space(3))) unsigned int*)l, 16, 0, 0);
}

// Encoding tables, 32 bf16 slots per point (64 B records):
//  A (center, pass1-biased): (xh,xl,xh)(yh,yl,yh)(zh,zl,zh); 9,10 = 1.0;
//    11+lab = -1024; 31 = -1024. Pass2 masks slots 11..31 to 0 in regs.
//  B (candidate, stored pre-XOR-swizzled by (i>>1)&3 in 16B groups):
//    (xh,xh,xl)(yh,yh,yl)(zh,zh,zl); 9,10 = -h_hi,-h_lo (h=0.5|v|^2);
//    11+lab = 1.0; 31 = 1.0 iff lab==-1.
__global__ __launch_bounds__(THREADS) void k_enc(const float* __restrict__ coord,
                                                 const int* __restrict__ seg,
                                                 unsigned short* __restrict__ aenc,
                                                 unsigned short* __restrict__ benc,
                                                 float* __restrict__ accum,
                                                 unsigned* __restrict__ done) {
    const int i = blockIdx.x * THREADS + threadIdx.x;
    float x = coord[3 * i], y = coord[3 * i + 1], z = coord[3 * i + 2];
    int lab = seg[i];
    unsigned short xh = f2bf(x), yh = f2bf(y), zh = f2bf(z);
    unsigned short xl = f2bf(x - bf2f(xh));
    unsigned short yl = f2bf(y - bf2f(yh));
    unsigned short zl = f2bf(z - bf2f(zh));
    float h = 0.5f * fmaf(x, x, fmaf(y, y, z * z));
    unsigned short hh = f2bf(h);
    unsigned short hl = f2bf(h - bf2f(hh));
    const unsigned short one = 0x3F80u, nb = 0xC480u;  // 1.0, -1024.0

    __attribute__((aligned(16))) unsigned short a[32], b[32];
    a[0] = xh; a[1] = xl; a[2] = xh;
    a[3] = yh; a[4] = yl; a[5] = yh;
    a[6] = zh; a[7] = zl; a[8] = zh;
    a[9] = one; a[10] = one;
#pragma unroll
    for (int s = 0; s < NCLS; s++) a[11 + s] = (lab == s) ? nb : 0u;
    a[31] = nb;

    b[0] = xh; b[1] = xh; b[2] = xl;
    b[3] = yh; b[4] = yh; b[5] = yl;
    b[6] = zh; b[7] = zh; b[8] = zl;
    b[9]  = hh ^ 0x8000u;
    b[10] = hl ^ 0x8000u;
#pragma unroll
    for (int s = 0; s < NCLS; s++) b[11 + s] = (lab == s) ? one : 0u;
    b[31] = (lab < 0) ? one : 0u;

    short8* ap = (short8*)(aenc + (size_t)i * 32);
#pragma unroll
    for (int kb = 0; kb < 4; kb++) ap[kb] = ((const short8*)a)[kb];
    short8* bp = (short8*)(benc + (size_t)i * 32);
    const int swz = (i >> 1) & 3;
#pragma unroll
    for (int kb = 0; kb < 4; kb++) bp[kb ^ swz] = ((const short8*)b)[kb];

    if (i < 4) accum[i] = 0.f;
    if (i == 4) *done = 0u;
}

// Score matrix S[i][j] = a_i . b_j via mfma 16x16x32 bf16.
// PASS1: per-(row,split) max (same/invalid pushed to ~-1024) -> smax_part.
// PASS2: per-(row,split) count of s > row-threshold -> cnt_part.
template<bool PASS1>
__global__ __launch_bounds__(THREADS, 4) void k_pass(const unsigned short* __restrict__ aenc,
                                                     const unsigned short* __restrict__ benc,
                                                     float* __restrict__ smax_part,
                                                     int* __restrict__ cnt_part) {
    __shared__ __align__(16) unsigned short smem[CHUNK * 32];  // 64 KB
    __shared__ float thr_lds[RPB];
    const int tid  = threadIdx.x;
    const int lane = tid & 63, wave = tid >> 6;
    const int l15  = lane & 15, l4 = lane >> 4;
    const int rb   = blockIdx.x * RPB;
    const int split = blockIdx.y;
    const int cb   = split * CAND_PB;

    // ---- issue chunk-0 DMA first; prologue overlaps it ----
    {
        const char* gsrc = (const char*)benc + (size_t)cb * 64;
#pragma unroll
        for (int r = 0; r < 8; r++)
            gload16(gsrc + (wave * 8 + r) * 1024 + lane * 16,
                    (char*)smem + (wave * 8 + r) * 1024);
    }

    // ---- pass2: per-row threshold = max over the split partials ----
    if (!PASS1 && tid < RPB) {
        int row = rb + tid;
        float m = smax_part[row];
#pragma unroll
        for (int s = 1; s < CSPLIT; s++) m = fmaxf(m, smax_part[s * N_PTS + row]);
        thr_lds[tid] = m;
    }

    // ---- A fragments straight from global (L2-hot) ----
    const int r0 = rb + wave * RPW + l15;
    short8 af0 = *(const short8*)(aenc + (size_t)r0 * 32 + l4 * 8);
    short8 af1 = *(const short8*)(aenc + (size_t)(r0 + 16) * 32 + l4 * 8);
    if (!PASS1) {
        // zero label/bias slots (exact: masked products contribute +-0.0)
        union { short8 s; unsigned u[4]; } c0v, c1v;
        c0v.s = af0; c1v.s = af1;
        if (l4 == 1) {
            c0v.u[1] &= 0x0000FFFFu; c0v.u[2] = 0u; c0v.u[3] = 0u;
            c1v.u[1] &= 0x0000FFFFu; c1v.u[2] = 0u; c1v.u[3] = 0u;
        } else if (l4 >= 2) {
            c0v.u[0] = c0v.u[1] = c0v.u[2] = c0v.u[3] = 0u;
            c1v.u[0] = c1v.u[1] = c1v.u[2] = c1v.u[3] = 0u;
        }
        af0 = c0v.s; af1 = c1v.s;
    }

    __syncthreads();   // chunk-0 DMA drained + thr_lds visible

    float thr0[4], thr1[4];
    if (!PASS1) {
#pragma unroll
        for (int r = 0; r < 4; r++) {
            thr0[r] = thr_lds[wave * RPW + l4 * 4 + r];
            thr1[r] = thr_lds[wave * RPW + 16 + l4 * 4 + r];
        }
    }

    f32x4 rmax0, rmax1;
    int cv0[4], cv1[4];
#pragma unroll
    for (int r = 0; r < 4; r++) {
        rmax0[r] = -3.0e38f; rmax1[r] = -3.0e38f;
        cv0[r] = 0; cv1[r] = 0;
    }

    const short8* bp = (const short8*)smem;
    const int bidx = l15 * 4 + (l4 ^ ((l15 >> 1) & 3));
    const f32x4 zero = {0.f, 0.f, 0.f, 0.f};

    for (int cc = 0; cc < NCHUNK; cc++) {
        // ---- sweep: per 32 cands: 2 ds_read_b128 + 4 MFMA + reduce ----
#pragma unroll 4
        for (int c0 = 0; c0 < CHUNK; c0 += 32) {
            short8 bA = bp[bidx + c0 * 4];
            short8 bB = bp[bidx + (c0 + 16) * 4];
            f32x4 dA0 = __builtin_amdgcn_mfma_f32_16x16x32_bf16(af0, bA, zero, 0, 0, 0);
            f32x4 dA1 = __builtin_amdgcn_mfma_f32_16x16x32_bf16(af1, bA, zero, 0, 0, 0);
            f32x4 dB0 = __builtin_amdgcn_mfma_f32_16x16x32_bf16(af0, bB, zero, 0, 0, 0);
            f32x4 dB1 = __builtin_amdgcn_mfma_f32_16x16x32_bf16(af1, bB, zero, 0, 0, 0);
            if (PASS1) {
#pragma unroll
                for (int r = 0; r < 4; r++) {
                    rmax0[r] = fmaxf(fmaxf(rmax0[r], dA0[r]), dB0[r]);
                    rmax1[r] = fmaxf(fmaxf(rmax1[r], dA1[r]), dB1[r]);
                }
            } else {
#pragma unroll
                for (int r = 0; r < 4; r++) {
                    cv0[r] += ((dA0[r] > thr0[r]) ? 1 : 0) + ((dB0[r] > thr0[r]) ? 1 : 0);
                    cv1[r] += ((dA1[r] > thr1[r]) ? 1 : 0) + ((dB1[r] > thr1[r]) ? 1 : 0);
                }
            }
        }
        // ---- stage next chunk (DMA only) ----
        if (cc + 1 < NCHUNK) {
            __syncthreads();
            const char* gsrc = (const char*)benc + (size_t)(cb + (cc + 1) * CHUNK) * 64;
#pragma unroll
            for (int r = 0; r < 8; r++)
                gload16(gsrc + (wave * 8 + r) * 1024 + lane * 16,
                        (char*)smem + (wave * 8 + r) * 1024);
            __syncthreads();
        }
    }

    // ---- reduce across the 16 column-lanes; write per-split partial ----
    const int row0 = rb + wave * RPW + l4 * 4;
    if (PASS1) {
#pragma unroll
        for (int m = 1; m < 16; m <<= 1)
#pragma unroll
            for (int r = 0; r < 4; r++) {
                rmax0[r] = fmaxf(rmax0[r], __shfl_xor(rmax0[r], m, 64));
                rmax1[r] = fmaxf(rmax1[r], __shfl_xor(rmax1[r], m, 64));
            }
        if (l15 == 0) {
#pragma unroll
            for (int r = 0; r < 4; r++) {
                smax_part[split * N_PTS + row0 + r]      = rmax0[r];
                smax_part[split * N_PTS + row0 + 16 + r] = rmax1[r];
            }
        }
    } else {
#pragma unroll
        for (int m = 1; m < 16; m <<= 1)
#pragma unroll
            for (int r = 0; r < 4; r++) {
                cv0[r] += __shfl_xor(cv0[r], m, 64);
                cv1[r] += __shfl_xor(cv1[r], m, 64);
            }
        if (l15 == 0) {
#pragma unroll
            for (int r = 0; r < 4; r++) {
                cnt_part[split * N_PTS + row0 + r]      = cv0[r];
                cnt_part[split * N_PTS + row0 + 16 + r] = cv1[r];
            }
        }
    }
}

__device__ __forceinline__ float waveReduceSum(float v) {
#pragma unroll
    for (int off = 32; off > 0; off >>= 1) v += __shfl_down(v, off, 64);
    return v;
}

// CE + masked accumulation; last block finalizes the loss (done-counter).
__global__ __launch_bounds__(256) void k_ce(const float* __restrict__ logits,
                                            const int* __restrict__ seg,
                                            const int* __restrict__ cnt_part,
                                            float* __restrict__ accum,
                                            unsigned* __restrict__ done,
                                            float* __restrict__ out) {
    const int i = blockIdx.x * 256 + threadIdx.x;
    float s_main = 0.f, n_main = 0.f, s_bnd = 0.f, n_bnd = 0.f;
    {
        int s = seg[i];
        bool valid = (s != -1);
        const float4* row4 = (const float4*)(logits + (size_t)i * NCLS);
        float a[NCLS];
        float4 v0 = row4[0], v1 = row4[1], v2 = row4[2], v3 = row4[3], v4 = row4[4];
        a[0]=v0.x; a[1]=v0.y; a[2]=v0.z; a[3]=v0.w;
        a[4]=v1.x; a[5]=v1.y; a[6]=v1.z; a[7]=v1.w;
        a[8]=v2.x; a[9]=v2.y; a[10]=v2.z; a[11]=v2.w;
        a[12]=v3.x; a[13]=v3.y; a[14]=v3.z; a[15]=v3.w;
        a[16]=v4.x; a[17]=v4.y; a[18]=v4.z; a[19]=v4.w;
        float m = a[0];
#pragma unroll
        for (int c = 1; c < NCLS; c++) m = fmaxf(m, a[c]);
        float se = 0.f;
#pragma unroll
        for (int c = 0; c < NCLS; c++) se += __expf(a[c] - m);
        int tgt = min(max(s, 0), NCLS - 1);
        float at = 0.f;
#pragma unroll
        for (int c = 0; c < NCLS; c++) at += (c == tgt) ? a[c] : 0.f;
        float logp = at - m - __logf(se);
        int cnt = 0;
#pragma unroll
        for (int sp = 0; sp < CSPLIT; sp++) cnt += cnt_part[sp * N_PTS + i];
        // cnt includes self exactly once; boundary iff rank of nearest diff < K
        bool bnd = valid && ((cnt - 1) < KNN);
        if (valid) { s_main = logp; n_main = 1.f; }
        if (bnd)   { s_bnd  = logp; n_bnd  = 1.f; }
    }
    s_main = waveReduceSum(s_main);
    n_main = waveReduceSum(n_main);
    s_bnd  = waveReduceSum(s_bnd);
    n_bnd  = waveReduceSum(n_bnd);
    if ((threadIdx.x & 63) == 0) {
        atomicAdd(&accum[0], s_main);
        atomicAdd(&accum[1], n_main);
        atomicAdd(&accum[2], s_bnd);
        atomicAdd(&accum[3], n_bnd);
    }
    __syncthreads();
    if (threadIdx.x == 0) {
        __threadfence();
        unsigned old = atomicAdd(done, 1u);
        if (old == gridDim.x - 1) {
            float sm = atomicAdd(&accum[0], 0.f);
            float cm = atomicAdd(&accum[1], 0.f);
            float sb = atomicAdd(&accum[2], 0.f);
            float cb = atomicAdd(&accum[3], 0.f);
            float main_loss = (cm > 0.f) ? (-sm / fmaxf(cm, 1.f)) : 0.f;
            float bnd_loss  = (cb > 0.f) ? (-sb / fmaxf(cb, 1.f)) : 0.f;
            out[0] = main_loss + BND_W * bnd_loss;
        }
    }
}

extern "C" void kernel_launch(void* const* d_in, const int* in_sizes, int n_in,
                              void* d_out, int out_size, void* d_ws, size_t ws_size,
                              hipStream_t stream) {
    const float* coord  = (const float*)d_in[0];
    const float* logits = (const float*)d_in[1];
    const int*   seg    = (const int*)d_in[2];
    (void)in_sizes; (void)n_in; (void)out_size; (void)ws_size;

    unsigned short* aenc = (unsigned short*)d_ws;                            // 1 MB
    unsigned short* benc = (unsigned short*)((char*)d_ws + (1u << 20));      // 1 MB
    float* smax_part = (float*)((char*)d_ws + (2u << 20));                   // 512 KB
    int*   cnt_part  = (int*)((char*)d_ws + (2u << 20) + (512u << 10));      // 512 KB
    float* accum     = (float*)((char*)d_ws + (3u << 20));
    unsigned* done   = (unsigned*)((char*)d_ws + (3u << 20) + 16);

    dim3 grid(RBLKS, CSPLIT);
    k_enc        <<<N_PTS / THREADS, THREADS, 0, stream>>>(coord, seg, aenc, benc, accum, done);
    k_pass<true> <<<grid, THREADS, 0, stream>>>(aenc, benc, smax_part, cnt_part);
    k_pass<false><<<grid, THREADS, 0, stream>>>(aenc, benc, smax_part, cnt_part);
    k_ce         <<<N_PTS / 256, 256, 0, stream>>>(logits, seg, cnt_part, accum, done, (float*)d_out);
}

// Round 7
// 64.024 us; speedup vs baseline: 1.0146x; 1.0146x over previous
//
#include <hip/hip_runtime.h>
#include <hip/hip_bf16.h>
#include <math.h>

#define N_PTS 16384
#define KNN   16
#define NCLS  20
#define BND_W 1.0f

#define THREADS 512
#define WAVES   8
#define FR      4                    // A fragments per wave
#define RPW     (16 * FR)            // 64 rows per wave
#define RPB     (WAVES * RPW)        // 512 rows per block
#define RBLKS   (N_PTS / RPB)        // 32 row-groups
#define CSPLIT  16
#define CAND_PB (N_PTS / CSPLIT)     // 1024 candidates per block (one 64 KB chunk)

typedef short  short8 __attribute__((ext_vector_type(8)));
typedef float  f32x4  __attribute__((ext_vector_type(4)));

// ---- bf16 helpers (RNE) ----
__device__ __forceinline__ unsigned short f2bf(float x) {
    union { __hip_bfloat16 h; unsigned short u; } cv;
    cv.h = __float2bfloat16(x);
    return cv.u;
}
__device__ __forceinline__ float bf2f(unsigned short b) {
    union { __hip_bfloat16 h; unsigned short u; } cv;
    cv.u = b;
    return __bfloat162float(cv.h);
}

// Candidate encoding (B), 32 bf16 slots:
//  0..8: (xh,xh,xl)(yh,yh,yl)(zh,zh,zl); 9,10: -h_hi,-h_lo (h=0.5|v|^2);
//  11..30: one-hot(label)=1.0; 31: 1.0 iff label==-1
__device__ __forceinline__ void build_b(const float* __restrict__ coord,
                                        const int* __restrict__ seg, int j,
                                        unsigned short* out) {
    float x = coord[3 * j], y = coord[3 * j + 1], z = coord[3 * j + 2];
    int lab = seg[j];
    unsigned short xh = f2bf(x), yh = f2bf(y), zh = f2bf(z);
    unsigned short xl = f2bf(x - bf2f(xh));
    unsigned short yl = f2bf(y - bf2f(yh));
    unsigned short zl = f2bf(z - bf2f(zh));
    float h = 0.5f * fmaf(x, x, fmaf(y, y, z * z));
    unsigned short hh = f2bf(h);
    unsigned short hl = f2bf(h - bf2f(hh));
    out[0] = xh; out[1] = xh; out[2] = xl;
    out[3] = yh; out[4] = yh; out[5] = yl;
    out[6] = zh; out[7] = zh; out[8] = zl;
    out[9]  = hh ^ 0x8000u;
    out[10] = hl ^ 0x8000u;
#pragma unroll
    for (int s = 0; s < NCLS; s++) out[11 + s] = (lab == s) ? 0x3F80u : 0u;
    out[31] = (lab < 0) ? 0x3F80u : 0u;
}

// Center (A) fragment built directly in registers. Slot table:
//  0..8: (xh,xl,xh)(yh,yl,yh)(zh,zl,zh); 9,10: 1.0;
//  PASS1: slot 11+lab = -1024, slot 31 = -1024; PASS2: those slots 0.
// Lane supplies row's slots g*8 .. g*8+7 (g = lane>>4).
template<bool PASS1>
__device__ __forceinline__ short8 build_a_frag(const float* __restrict__ coord,
                                               const int* __restrict__ seg,
                                               int row, int g) {
    __attribute__((aligned(16))) unsigned short s[8];
    const unsigned short one = 0x3F80u;
    const unsigned short nb = PASS1 ? 0xC480u : 0u;   // -1024.0 or 0
    if (g == 0) {
        float x = coord[3 * row], y = coord[3 * row + 1], z = coord[3 * row + 2];
        unsigned short xh = f2bf(x), yh = f2bf(y), zh = f2bf(z);
        s[0] = xh; s[1] = f2bf(x - bf2f(xh)); s[2] = xh;
        s[3] = yh; s[4] = f2bf(y - bf2f(yh)); s[5] = yh;
        s[6] = zh; s[7] = f2bf(z - bf2f(zh));
    } else if (g == 1) {
        float z = coord[3 * row + 2];
        int lab = seg[row];
        s[0] = f2bf(z); s[1] = one; s[2] = one;
        s[3] = (lab == 0) ? nb : 0u; s[4] = (lab == 1) ? nb : 0u;
        s[5] = (lab == 2) ? nb : 0u; s[6] = (lab == 3) ? nb : 0u;
        s[7] = (lab == 4) ? nb : 0u;
    } else if (g == 2) {
        int lab = seg[row];
        s[0] = (lab == 5) ? nb : 0u;  s[1] = (lab == 6) ? nb : 0u;
        s[2] = (lab == 7) ? nb : 0u;  s[3] = (lab == 8) ? nb : 0u;
        s[4] = (lab == 9) ? nb : 0u;  s[5] = (lab == 10) ? nb : 0u;
        s[6] = (lab == 11) ? nb : 0u; s[7] = (lab == 12) ? nb : 0u;
    } else {
        int lab = seg[row];
        s[0] = (lab == 13) ? nb : 0u; s[1] = (lab == 14) ? nb : 0u;
        s[2] = (lab == 15) ? nb : 0u; s[3] = (lab == 16) ? nb : 0u;
        s[4] = (lab == 17) ? nb : 0u; s[5] = (lab == 18) ? nb : 0u;
        s[6] = (lab == 19) ? nb : 0u; s[7] = nb;  // slot 31 (invalid-cand mask)
    }
    return *(const short8*)s;
}

__device__ __forceinline__ float waveReduceSum(float v) {
#pragma unroll
    for (int off = 32; off > 0; off >>= 1) v += __shfl_down(v, off, 64);
    return v;
}

// PASS1: per-(row,split) max of biased scores -> smax_part[split][row].
// PASS2: count s > thr per row (atomicAdd cnt); last split-block per row-group
//        runs CE for its 512 rows; last CE block writes the scalar loss.
template<bool PASS1>
__global__ __launch_bounds__(THREADS, 4) void k_pass(
    const float* __restrict__ coord, const int* __restrict__ seg,
    const float* __restrict__ logits,
    float* __restrict__ smax_part, int* __restrict__ cnt,
    float* __restrict__ accum, int* __restrict__ done_rb,
    unsigned* __restrict__ done_final, float* __restrict__ out)
{
    __shared__ __align__(16) unsigned short bsm[CAND_PB * 32];  // 64 KB
    __shared__ float thr_lds[RPB];
    __shared__ int s_flag;
    const int tid  = threadIdx.x;
    const int lane = tid & 63, wave = tid >> 6;
    const int l15  = lane & 15, l4 = lane >> 4;
    const int rb   = blockIdx.x * RPB;
    const int split = blockIdx.y;
    const int cb   = split * CAND_PB;

    if (PASS1 && split == 0) {
        cnt[rb + tid] = 0;                       // zeroed before pass2's atomics
        if (tid == 5) done_rb[blockIdx.x] = 0;
        if (blockIdx.x == 0) {
            if (tid < 4) accum[tid] = 0.f;
            if (tid == 4) *done_final = 0u;
        }
    }

    // ---- stage B chunk: 2 candidates per thread, XOR-swizzled ds_write ----
    {
        __attribute__((aligned(16))) unsigned short be[32];
        short8* wp = (short8*)bsm;
#pragma unroll
        for (int u = 0; u < 2; u++) {
            int c = 2 * tid + u;
            build_b(coord, seg, cb + c, be);
            int swz = (c >> 1) & 3;
#pragma unroll
            for (int kb = 0; kb < 4; kb++)
                wp[c * 4 + (kb ^ swz)] = ((const short8*)be)[kb];
        }
    }

    // ---- A fragments straight into registers ----
    short8 af[FR];
#pragma unroll
    for (int f = 0; f < FR; f++)
        af[f] = build_a_frag<PASS1>(coord, seg, rb + wave * RPW + f * 16 + l15, l4);

    // ---- pass2: per-row threshold = max over the 16 split partials ----
    if (!PASS1) {
        int row = rb + tid;
        float m = smax_part[row];
#pragma unroll
        for (int s = 1; s < CSPLIT; s++) m = fmaxf(m, smax_part[s * N_PTS + row]);
        thr_lds[tid] = m;
    }
    __syncthreads();

    float thr[FR][4];
    if (!PASS1) {
#pragma unroll
        for (int f = 0; f < FR; f++)
#pragma unroll
            for (int r = 0; r < 4; r++)
                thr[f][r] = thr_lds[wave * RPW + f * 16 + l4 * 4 + r];
    }

    f32x4 rmax[FR];
    int cv[FR][4];
#pragma unroll
    for (int f = 0; f < FR; f++)
#pragma unroll
        for (int r = 0; r < 4; r++) { rmax[f][r] = -3.0e38f; cv[f][r] = 0; }

    const short8* bp = (const short8*)bsm;
    const int bidx = l15 * 4 + (l4 ^ ((l15 >> 1) & 3));
    const f32x4 zero = {0.f, 0.f, 0.f, 0.f};

    // ---- sweep: per 32 cands: 2 ds_read_b128 + 8 MFMA (1 KB feeds 8 MFMA) ----
#pragma unroll 2
    for (int c0 = 0; c0 < CAND_PB; c0 += 32) {
        short8 bA = bp[bidx + c0 * 4];
        short8 bB = bp[bidx + (c0 + 16) * 4];
        f32x4 dA[FR], dB[FR];
#pragma unroll
        for (int f = 0; f < FR; f++)
            dA[f] = __builtin_amdgcn_mfma_f32_16x16x32_bf16(af[f], bA, zero, 0, 0, 0);
#pragma unroll
        for (int f = 0; f < FR; f++)
            dB[f] = __builtin_amdgcn_mfma_f32_16x16x32_bf16(af[f], bB, zero, 0, 0, 0);
        if (PASS1) {
#pragma unroll
            for (int f = 0; f < FR; f++)
#pragma unroll
                for (int r = 0; r < 4; r++)
                    rmax[f][r] = fmaxf(fmaxf(rmax[f][r], dA[f][r]), dB[f][r]);
        } else {
#pragma unroll
            for (int f = 0; f < FR; f++)
#pragma unroll
                for (int r = 0; r < 4; r++)
                    cv[f][r] += ((dA[f][r] > thr[f][r]) ? 1 : 0)
                              + ((dB[f][r] > thr[f][r]) ? 1 : 0);
        }
    }

    // ---- reduce across the 16 column-lanes; write ----
    if (PASS1) {
#pragma unroll
        for (int m = 1; m < 16; m <<= 1)
#pragma unroll
            for (int f = 0; f < FR; f++)
#pragma unroll
                for (int r = 0; r < 4; r++)
                    rmax[f][r] = fmaxf(rmax[f][r], __shfl_xor(rmax[f][r], m, 64));
        if (l15 == 0) {
#pragma unroll
            for (int f = 0; f < FR; f++)
#pragma unroll
                for (int r = 0; r < 4; r++)
                    smax_part[split * N_PTS + rb + wave * RPW + f * 16 + l4 * 4 + r] = rmax[f][r];
        }
    } else {
#pragma unroll
        for (int m = 1; m < 16; m <<= 1)
#pragma unroll
            for (int f = 0; f < FR; f++)
#pragma unroll
                for (int r = 0; r < 4; r++)
                    cv[f][r] += __shfl_xor(cv[f][r], m, 64);
        if (l15 == 0) {
#pragma unroll
            for (int f = 0; f < FR; f++)
#pragma unroll
                for (int r = 0; r < 4; r++)
                    atomicAdd(&cnt[rb + wave * RPW + f * 16 + l4 * 4 + r], cv[f][r]);
        }

        // ---- CE tail: last split-block of this row-group handles its 512 rows ----
        __syncthreads();
        if (tid == 0) {
            __threadfence();
            s_flag = (atomicAdd(&done_rb[blockIdx.x], 1) == CSPLIT - 1) ? 1 : 0;
        }
        __syncthreads();
        if (s_flag) {
            const int row = rb + tid;
            int sg = seg[row];
            bool valid = (sg != -1);
            const float4* row4 = (const float4*)(logits + (size_t)row * NCLS);
            float a[NCLS];
            float4 v0 = row4[0], v1 = row4[1], v2 = row4[2], v3 = row4[3], v4 = row4[4];
            a[0]=v0.x; a[1]=v0.y; a[2]=v0.z; a[3]=v0.w;
            a[4]=v1.x; a[5]=v1.y; a[6]=v1.z; a[7]=v1.w;
            a[8]=v2.x; a[9]=v2.y; a[10]=v2.z; a[11]=v2.w;
            a[12]=v3.x; a[13]=v3.y; a[14]=v3.z; a[15]=v3.w;
            a[16]=v4.x; a[17]=v4.y; a[18]=v4.z; a[19]=v4.w;
            float mx = a[0];
#pragma unroll
            for (int c = 1; c < NCLS; c++) mx = fmaxf(mx, a[c]);
            float se = 0.f;
#pragma unroll
            for (int c = 0; c < NCLS; c++) se += __expf(a[c] - mx);
            int tgt = min(max(sg, 0), NCLS - 1);
            float at = 0.f;
#pragma unroll
            for (int c = 0; c < NCLS; c++) at += (c == tgt) ? a[c] : 0.f;
            float logp = at - mx - __logf(se);
            int crow = atomicAdd(&cnt[row], 0);   // coherent read
            // cnt includes self once; boundary iff rank of nearest-diff < K
            bool bnd = valid && ((crow - 1) < KNN);
            float sm = valid ? logp : 0.f, nm = valid ? 1.f : 0.f;
            float sb = bnd ? logp : 0.f,  nb2 = bnd ? 1.f : 0.f;
            sm = waveReduceSum(sm); nm = waveReduceSum(nm);
            sb = waveReduceSum(sb); nb2 = waveReduceSum(nb2);
            if ((tid & 63) == 0) {
                atomicAdd(&accum[0], sm);
                atomicAdd(&accum[1], nm);
                atomicAdd(&accum[2], sb);
                atomicAdd(&accum[3], nb2);
            }
            __syncthreads();
            if (tid == 0) {
                __threadfence();
                if (atomicAdd(done_final, 1u) == (unsigned)(RBLKS - 1)) {
                    float Sm = atomicAdd(&accum[0], 0.f);
                    float Cm = atomicAdd(&accum[1], 0.f);
                    float Sb = atomicAdd(&accum[2], 0.f);
                    float Cb = atomicAdd(&accum[3], 0.f);
                    float main_loss = (Cm > 0.f) ? (-Sm / fmaxf(Cm, 1.f)) : 0.f;
                    float bnd_loss  = (Cb > 0.f) ? (-Sb / fmaxf(Cb, 1.f)) : 0.f;
                    out[0] = main_loss + BND_W * bnd_loss;
                }
            }
        }
    }
}

extern "C" void kernel_launch(void* const* d_in, const int* in_sizes, int n_in,
                              void* d_out, int out_size, void* d_ws, size_t ws_size,
                              hipStream_t stream) {
    const float* coord  = (const float*)d_in[0];
    const float* logits = (const float*)d_in[1];
    const int*   seg    = (const int*)d_in[2];
    (void)in_sizes; (void)n_in; (void)out_size; (void)ws_size;

    float*    smax_part = (float*)d_ws;                                  // [16][N] f32, 1 MB
    int*      cnt       = (int*)((char*)d_ws + CSPLIT * N_PTS * 4);      // [N] i32, 64 KB
    char*     tail      = (char*)d_ws + CSPLIT * N_PTS * 4 + N_PTS * 4;
    float*    accum     = (float*)tail;                                  // 4 f32
    int*      done_rb   = (int*)(tail + 16);                             // 32 i32
    unsigned* done_final= (unsigned*)(tail + 16 + RBLKS * 4);

    dim3 grid(RBLKS, CSPLIT);
    k_pass<true> <<<grid, THREADS, 0, stream>>>(coord, seg, logits, smax_part, cnt,
                                                accum, done_rb, done_final, (float*)d_out);
    k_pass<false><<<grid, THREADS, 0, stream>>>(coord, seg, logits, smax_part, cnt,
                                                accum, done_rb, done_final, (float*)d_out);
}